// Round 3
// baseline (660.557 us; speedup 1.0000x reference)
//
#include <hip/hip_runtime.h>
#include <math.h>

#define PDIM 8
#define BSZ 256
#define CEEG 22
#define TLEN 1000
#define KW 12
#define C2 96
#define TOUT 989
#define TSTR 992          // padded h2 row stride (16B-aligned float4 stores)
#define NSWEEP 8

// ---- workspace layout (in floats) ----
#define OFF_H1   ((size_t)0)
#define SZ_H1    ((size_t)BSZ*CEEG*TLEN)
#define OFF_H2   (OFF_H1 + SZ_H1)
#define SZ_H2    ((size_t)BSZ*C2*TSTR)
#define OFF_S    (OFF_H2 + SZ_H2)
#define SZ_S     ((size_t)BSZ*3*1024)
#define OFF_QQT  (OFF_S + SZ_S)
#define SZ_QQT   ((size_t)BSZ*3*256)
#define OFF_KKT  (OFF_QQT + SZ_QQT)
#define OFF_VP   (OFF_KKT + SZ_QQT)
#define SZ_VP    ((size_t)BSZ*256)
#define OFF_P1   (OFF_VP + SZ_VP)
#define SZ_P1    ((size_t)BSZ*44)
#define OFF_P2   (OFF_P1 + SZ_P1)
#define SZ_P2    ((size_t)BSZ*8*192)
#define OFF_BN1  (OFF_P2 + SZ_P2)
#define OFF_BN2  (OFF_BN1 + (size_t)64)

// ================= K1: conv1 (22ch spatial filter) + BN1 partial stats ==========
__global__ __launch_bounds__(256) void k1_conv1(const float* __restrict__ x,
        const float* __restrict__ w1, float* __restrict__ h1,
        float* __restrict__ part1) {
    __shared__ float sw[CEEG*CEEG];       // [o][c]
    __shared__ float red[4][44];
    int b = blockIdx.x;
    int tid = threadIdx.x;
    for (int i = tid; i < CEEG*CEEG; i += 256) sw[i] = w1[i];
    __syncthreads();
    float sum[CEEG], sumsq[CEEG];
    #pragma unroll
    for (int o = 0; o < CEEG; ++o) { sum[o] = 0.f; sumsq[o] = 0.f; }
    const float* xb = x + (size_t)b*CEEG*TLEN;
    float* hb = h1 + (size_t)b*CEEG*TLEN;
    for (int it = 0; it < 4; ++it) {
        int t = it*256 + tid;
        if (t < TLEN) {
            float acc[CEEG];
            #pragma unroll
            for (int o = 0; o < CEEG; ++o) acc[o] = 0.f;
            #pragma unroll 2
            for (int c = 0; c < CEEG; ++c) {
                float xv = xb[c*TLEN + t];
                #pragma unroll
                for (int o = 0; o < CEEG; ++o) acc[o] = fmaf(xv, sw[o*CEEG + c], acc[o]);
            }
            #pragma unroll
            for (int o = 0; o < CEEG; ++o) {
                hb[o*TLEN + t] = acc[o];
                sum[o]  += acc[o];
                sumsq[o] += acc[o]*acc[o];
            }
        }
    }
    int lane = tid & 63, wv = tid >> 6;
    #pragma unroll
    for (int o = 0; o < CEEG; ++o) {
        float s = sum[o], s2 = sumsq[o];
        for (int off = 32; off > 0; off >>= 1) {
            s  += __shfl_down(s,  off, 64);
            s2 += __shfl_down(s2, off, 64);
        }
        if (lane == 0) { red[wv][o] = s; red[wv][CEEG + o] = s2; }
    }
    __syncthreads();
    if (tid < 44) {
        part1[(size_t)b*44 + tid] = red[0][tid] + red[1][tid] + red[2][tid] + red[3][tid];
    }
}

// ================= K2: finalize BN1 params (1 block / channel) ==========
__global__ __launch_bounds__(64) void k2_bn1(const float* __restrict__ part1,
        const float* __restrict__ g, const float* __restrict__ bta, float* __restrict__ p1) {
    int c = blockIdx.x, t = threadIdx.x;
    float s = 0.f, s2 = 0.f;
    for (int blk = t; blk < BSZ; blk += 64) {
        s  += part1[(size_t)blk*44 + c];
        s2 += part1[(size_t)blk*44 + CEEG + c];
    }
    for (int off = 32; off > 0; off >>= 1) {
        s  += __shfl_down(s,  off, 64);
        s2 += __shfl_down(s2, off, 64);
    }
    if (t == 0) {
        double N = (double)BSZ * (double)TLEN;
        double mu = (double)s / N, var = (double)s2 / N - mu*mu;
        double scale = (double)g[c] / sqrt(var + 1e-5);
        p1[c] = (float)scale;
        p1[CEEG + c] = (float)((double)bta[c] - mu*scale);
    }
}

// ================= K3: conv2 (96x22x12) v2: 3o x 16t / thread, dbuf weights ====
__global__ __launch_bounds__(256) void k3_conv2(const float* __restrict__ h1,
        const float* __restrict__ w2, const float* __restrict__ p1,
        float* __restrict__ h2, float* __restrict__ part2) {
    __shared__ float sin_[CEEG][160];       // staged input (BN1+ELU), 16B-aligned rows
    __shared__ float swt[2][C2*14];         // double-buffered weights [o][14]
    __shared__ float rStat[C2][20];         // per-(o, tgroup) partial sums
    int b = blockIdx.x;
    int tile = blockIdx.y;                  // 0..7
    int t0 = tile * 128;
    int tid = threadIdx.x;
    int og = tid & 31;                      // o base = 3*og
    int tg = tid >> 5;                      // t base = 16*tg
    int ob = 3*og;
    const float* hb = h1 + (size_t)b*CEEG*TLEN;

    // stage input window [t0, t0+139] with BN1+ELU; zero beyond TLEN
    for (int i = tid; i < CEEG*140; i += 256) {
        int c = i / 140, tt = i - c*140;
        float v = 0.f;
        int t = t0 + tt;
        if (t < TLEN) {
            float z = fmaf(hb[c*TLEN + t], p1[c], p1[CEEG + c]);
            v = z > 0.f ? z : expm1f(z);
        }
        sin_[c][tt] = v;
    }
    // stage weights for c=0 into buf 0
    for (int i = tid; i < C2*KW; i += 256) {
        int o = i / KW, k = i - o*KW;
        swt[0][o*14 + k] = w2[o*264 + k];   // c=0
    }
    __syncthreads();

    float acc[3][16];
    #pragma unroll
    for (int j = 0; j < 3; ++j)
        #pragma unroll
        for (int i = 0; i < 16; ++i) acc[j][i] = 0.f;

    for (int c = 0; c < CEEG; ++c) {
        int buf = c & 1;
        // prefetch weights for c+1 into other buffer
        if (c + 1 < CEEG) {
            int cn = c + 1;
            for (int i = tid; i < C2*KW; i += 256) {
                int o = i / KW, k = i - o*KW;
                swt[buf ^ 1][o*14 + k] = w2[o*264 + cn*12 + k];
            }
        }
        // load this thread's weights (float2, 2-way bank alias = free)
        float aw[3][12];
        #pragma unroll
        for (int j = 0; j < 3; ++j) {
            const float2* wr = (const float2*)&swt[buf][(ob + j)*14];
            #pragma unroll
            for (int h = 0; h < 6; ++h) {
                float2 wv2 = wr[h];
                aw[j][2*h] = wv2.x; aw[j][2*h + 1] = wv2.y;
            }
        }
        // load input window (float4 broadcast: 2 distinct addrs per wave)
        float bw[28];
        const float4* br = (const float4*)&sin_[c][tg*16];
        #pragma unroll
        for (int h = 0; h < 7; ++h) {
            float4 bv = br[h];
            bw[4*h] = bv.x; bw[4*h+1] = bv.y; bw[4*h+2] = bv.z; bw[4*h+3] = bv.w;
        }
        #pragma unroll
        for (int k = 0; k < KW; ++k) {
            #pragma unroll
            for (int j = 0; j < 3; ++j) {
                float a = aw[j][k];
                #pragma unroll
                for (int i = 0; i < 16; ++i)
                    acc[j][i] = fmaf(a, bw[i + k], acc[j][i]);
            }
        }
        __syncthreads();
    }

    // stores + BN2 partial stats
    float* h2b = h2 + (size_t)b*C2*TSTR;
    int tbase = t0 + tg*16;
    #pragma unroll
    for (int j = 0; j < 3; ++j) {
        int o = ob + j;
        float s = 0.f, s2 = 0.f;
        if (tbase + 15 < TOUT) {
            float* dst = &h2b[(size_t)o*TSTR + tbase];
            #pragma unroll
            for (int h = 0; h < 4; ++h) {
                *(float4*)&dst[4*h] = make_float4(acc[j][4*h], acc[j][4*h+1], acc[j][4*h+2], acc[j][4*h+3]);
                #pragma unroll
                for (int u = 0; u < 4; ++u) {
                    float v = acc[j][4*h + u];
                    s += v; s2 += v*v;
                }
            }
        } else {
            #pragma unroll
            for (int i = 0; i < 16; ++i) {
                int t = tbase + i;
                if (t < TOUT) {
                    float v = acc[j][i];
                    h2b[(size_t)o*TSTR + t] = v;
                    s += v; s2 += v*v;
                }
            }
        }
        rStat[o][2*tg]     = s;
        rStat[o][2*tg + 1] = s2;
    }
    __syncthreads();
    if (tid < C2) {
        float s = 0.f, s2 = 0.f;
        #pragma unroll
        for (int g2 = 0; g2 < 8; ++g2) { s += rStat[tid][2*g2]; s2 += rStat[tid][2*g2+1]; }
        float* pb = part2 + ((size_t)b*8 + tile)*192;
        pb[tid] = s; pb[96 + tid] = s2;
    }
}

// ================= K4: finalize BN2 params (1 block / channel) ==========
__global__ __launch_bounds__(256) void k4_bn2(const float* __restrict__ part2,
        const float* __restrict__ g, const float* __restrict__ bta, float* __restrict__ p2) {
    __shared__ float rs[4], rs2[4];
    int q = blockIdx.x, t = threadIdx.x;
    float s = 0.f, s2 = 0.f;
    for (int blk = t; blk < BSZ*8; blk += 256) {
        s  += part2[(size_t)blk*192 + q];
        s2 += part2[(size_t)blk*192 + 96 + q];
    }
    for (int off = 32; off > 0; off >>= 1) {
        s  += __shfl_down(s,  off, 64);
        s2 += __shfl_down(s2, off, 64);
    }
    int lane = t & 63, wv = t >> 6;
    if (lane == 0) { rs[wv] = s; rs2[wv] = s2; }
    __syncthreads();
    if (t == 0) {
        double S  = (double)rs[0]  + rs[1]  + rs[2]  + rs[3];
        double S2 = (double)rs2[0] + rs2[1] + rs2[2] + rs2[3];
        double N = (double)BSZ * (double)TOUT;
        double mu = S / N, var = S2 / N - mu*mu;
        double scale = (double)g[q] / sqrt(var + 1e-5);
        p2[q] = (float)scale;
        p2[C2 + q] = (float)((double)bta[q] - mu*scale);
    }
}

// ================= K5: BN2+ELU fused Gram matrices S[b][m] = X X^T ==========
__global__ __launch_bounds__(256) void k5_gram(const float* __restrict__ h2,
        const float* __restrict__ p2, float* __restrict__ S) {
    __shared__ float sx[32][68];
    int bm = blockIdx.x;
    int b = bm / 3, m = bm % 3;
    int tid = threadIdx.x;
    int r0 = (tid >> 4) * 2;
    int c0 = (tid & 15) * 2;
    float a00 = 0.f, a01 = 0.f, a10 = 0.f, a11 = 0.f;
    const float* hb = h2 + ((size_t)b*C2 + m*32)*TSTR;
    int row = tid >> 3;
    int ts  = (tid & 7) * 8;
    float sc = p2[m*32 + row], sh = p2[C2 + m*32 + row];
    for (int t0 = 0; t0 < TOUT; t0 += 64) {
        __syncthreads();
        #pragma unroll
        for (int j = 0; j < 8; ++j) {
            int t = t0 + ts + j;
            float v = 0.f;
            if (t < TOUT) {
                float z = fmaf(hb[(size_t)row*TSTR + t], sc, sh);
                v = z > 0.f ? z : expm1f(z);
            }
            sx[row][ts + j] = v;
        }
        __syncthreads();
        #pragma unroll
        for (int tt = 0; tt < 64; tt += 4) {
            float4 va0 = *(const float4*)&sx[r0][tt];
            float4 va1 = *(const float4*)&sx[r0+1][tt];
            float4 vb0 = *(const float4*)&sx[c0][tt];
            float4 vb1 = *(const float4*)&sx[c0+1][tt];
            a00 = fmaf(va0.x, vb0.x, fmaf(va0.y, vb0.y, fmaf(va0.z, vb0.z, fmaf(va0.w, vb0.w, a00))));
            a01 = fmaf(va0.x, vb1.x, fmaf(va0.y, vb1.y, fmaf(va0.z, vb1.z, fmaf(va0.w, vb1.w, a01))));
            a10 = fmaf(va1.x, vb0.x, fmaf(va1.y, vb0.y, fmaf(va1.z, vb0.z, fmaf(va1.w, vb0.w, a10))));
            a11 = fmaf(va1.x, vb1.x, fmaf(va1.y, vb1.y, fmaf(va1.z, vb1.z, fmaf(va1.w, vb1.w, a11))));
        }
    }
    float* Sb = S + (size_t)bm*1024;
    Sb[r0*32 + c0]       = a00;
    Sb[r0*32 + c0 + 1]   = a01;
    Sb[(r0+1)*32 + c0]   = a10;
    Sb[(r0+1)*32 + c0+1] = a11;
}

// ================= K6: Jacobi eigh, one matrix per 64-thread wave ======
__device__ __forceinline__ void pair_of(int r, int k, int& p, int& q) {
    if (k == 0) { p = r; q = 31; }
    else {
        int a = (r + k) % 31;
        int b2 = (r - k + 31) % 31;
        p = min(a, b2); q = max(a, b2);
    }
}

__global__ __launch_bounds__(64) void k6_eig(const float* __restrict__ S,
        const float* __restrict__ wq, const float* __restrict__ wk, const float* __restrict__ wv,
        float* __restrict__ QQt, float* __restrict__ KKt, float* __restrict__ Vp) {
    __shared__ float A[32][33];
    __shared__ float Vv[32][33];
    __shared__ float csc[16], css[16];
    __shared__ float sW[3][512];
    __shared__ unsigned int ptab[31*16];
    __shared__ float Up[32][9];
    __shared__ float Aw[16][9];
    __shared__ float G[8][9];
    __shared__ float Lm[8][9];
    __shared__ float Mm[16][9];
    __shared__ float lam[32];
    int bm = blockIdx.x, b = bm / 3, m = bm % 3;
    int tid = threadIdx.x;                 // 0..63 (one wave)
    const float* Sb = S + (size_t)bm*1024;
    for (int i = tid; i < 1024; i += 64) {
        int r_ = i >> 5, c_ = i & 31;
        A[r_][c_] = Sb[i];
        Vv[r_][c_] = (r_ == c_) ? 1.f : 0.f;
    }
    for (int i = tid; i < 512; i += 64) {
        sW[0][i] = wq[i]; sW[1][i] = wk[i]; sW[2][i] = wv[i];
    }
    for (int i = tid; i < 31*16; i += 64) {
        int r_ = i >> 4, k_ = i & 15;
        int p, q; pair_of(r_, k_, p, q);
        ptab[i] = (unsigned)p | ((unsigned)q << 16);
    }
    __syncthreads();

    int b_ = tid & 15;        // this lane's col-pair
    int hi2 = tid >> 4;       // row-pair seed
    for (int sweep = 0; sweep < NSWEEP; ++sweep) {
        for (int r = 0; r < 31; ++r) {
            if (tid < 16) {
                unsigned pq = ptab[(r << 4) + tid];
                int p = pq & 0xffff, q = pq >> 16;
                float app = A[p][p], aqq = A[q][q], apq = A[p][q];
                float c = 1.f, s = 0.f;
                if (apq != 0.f) {
                    float tau = (aqq - app) / (2.f * apq);
                    float tt = (tau >= 0.f ? 1.f : -1.f) / (fabsf(tau) + sqrtf(1.f + tau*tau));
                    c = 1.f / sqrtf(1.f + tt*tt);
                    s = tt * c;
                    if (!(c == c) || !(s == s)) { c = 1.f; s = 0.f; }
                }
                csc[tid] = c; css[tid] = s;
            }
            __syncthreads();
            unsigned pql = ptab[(r << 4) + b_];
            int rr = pql & 0xffff, ss = pql >> 16;
            float cl = csc[b_], sl = css[b_];
            #pragma unroll
            for (int j = 0; j < 4; ++j) {
                int k2 = hi2 + (j << 2);
                unsigned pqk = ptab[(r << 4) + k2];
                int p = pqk & 0xffff, q = pqk >> 16;
                float ck = csc[k2], sk = css[k2];
                float apr = A[p][rr], aps = A[p][ss], aqr = A[q][rr], aqs = A[q][ss];
                float tpr = ck*apr - sk*aqr;
                float tqr = sk*apr + ck*aqr;
                float tps = ck*aps - sk*aqs;
                float tqs = sk*aps + ck*aqs;
                A[p][rr] = cl*tpr - sl*tps;
                A[p][ss] = sl*tpr + cl*tps;
                A[q][rr] = cl*tqr - sl*tqs;
                A[q][ss] = sl*tqr + cl*tqs;
                int i0 = k2 << 1;
                float v0r = Vv[i0][rr], v0s = Vv[i0][ss];
                Vv[i0][rr] = cl*v0r - sl*v0s;
                Vv[i0][ss] = sl*v0r + cl*v0s;
                float v1r = Vv[i0+1][rr], v1s = Vv[i0+1][ss];
                Vv[i0+1][rr] = cl*v1r - sl*v1s;
                Vv[i0+1][ss] = sl*v1r + cl*v1s;
            }
            __syncthreads();
        }
    }

    // top-8 eigenvalue selection (descending) -> Up
    if (tid < 32) lam[tid] = A[tid][tid];
    __syncthreads();
    if (tid < 32) {
        float lj = lam[tid];
        int rank = 0;
        #pragma unroll
        for (int i = 0; i < 32; ++i) {
            float li = lam[i];
            rank += (li > lj) || (li == lj && i < tid);
        }
        if (rank < PDIM) {
            #pragma unroll
            for (int i = 0; i < 32; ++i) Up[i][rank] = Vv[i][tid];
        }
    }
    __syncthreads();

    // projections: P = A (A^T A)^{-1} A^T for A = W * Up  (== qr(A).Q @ Q^T)
    for (int widx = 0; widx < 3; ++widx) {
        if (widx == 2 && m != 2) break;   // V-projection only needed for m==2
        const float* W = sW[widx];
        for (int i = tid; i < 128; i += 64) {
            int o = i >> 3, pp = i & 7;
            float s = 0.f;
            #pragma unroll
            for (int c_ = 0; c_ < 32; ++c_) s = fmaf(W[o*32 + c_], Up[c_][pp], s);
            Aw[o][pp] = s;
        }
        __syncthreads();
        {
            int xx = tid >> 3, yy = tid & 7;
            float s = 0.f;
            #pragma unroll
            for (int o = 0; o < 16; ++o) s = fmaf(Aw[o][xx], Aw[o][yy], s);
            G[xx][yy] = s;
        }
        __syncthreads();
        if (tid == 0) {
            float Lr[8][8];
            #pragma unroll
            for (int jj = 0; jj < 8; ++jj) {
                float d = G[jj][jj];
                #pragma unroll
                for (int kk = 0; kk < 8; ++kk) if (kk < jj) d -= Lr[jj][kk]*Lr[jj][kk];
                d = sqrtf(fmaxf(d, 1e-30f));
                float inv = 1.f / d;
                Lr[jj][jj] = d;
                Lm[jj][jj] = inv;     // store INVERSE of diagonal
                #pragma unroll
                for (int ii = 0; ii < 8; ++ii) if (ii > jj) {
                    float v = G[ii][jj];
                    #pragma unroll
                    for (int kk = 0; kk < 8; ++kk) if (kk < jj) v -= Lr[ii][kk]*Lr[jj][kk];
                    v *= inv;
                    Lr[ii][jj] = v;
                    Lm[ii][jj] = v;
                }
            }
        }
        __syncthreads();
        if (tid < 16) {
            int o = tid;
            float a[8], mv[8];
            #pragma unroll
            for (int pp = 0; pp < 8; ++pp) a[pp] = Aw[o][pp];
            #pragma unroll
            for (int jj = 0; jj < 8; ++jj) {
                float v = a[jj];
                #pragma unroll
                for (int kk = 0; kk < 8; ++kk) if (kk < jj) v -= Lm[jj][kk]*mv[kk];
                mv[jj] = v * Lm[jj][jj];
            }
            #pragma unroll
            for (int pp = 0; pp < 8; ++pp) Mm[o][pp] = mv[pp];
        }
        __syncthreads();
        {
            float* dst = (widx == 0) ? (QQt + (size_t)bm*256)
                       : (widx == 1) ? (KKt + (size_t)bm*256)
                       : (Vp + (size_t)b*256);
            for (int i = tid; i < 256; i += 64) {
                int d = i >> 4, e = i & 15;
                float s = 0.f;
                #pragma unroll
                for (int pp = 0; pp < 8; ++pp) s = fmaf(Mm[d][pp], Mm[e][pp], s);
                dst[d*16 + e] = s;
            }
        }
        __syncthreads();
    }
}

// ================= K7: attention scores + softmax(i=2) + output linear ==========
__global__ __launch_bounds__(64) void k7_out(const float* __restrict__ QQt,
        const float* __restrict__ KKt, const float* __restrict__ Vp,
        const float* __restrict__ lw, const float* __restrict__ lb,
        float* __restrict__ out) {
    __shared__ float sQ[3][256], sK[3][256], sVp[256], ssc[9], wj[3];
    int b = blockIdx.x, tid = threadIdx.x;
    for (int i = tid; i < 768; i += 64) {
        sQ[i >> 8][i & 255] = QQt[(size_t)b*768 + i];
        sK[i >> 8][i & 255] = KKt[(size_t)b*768 + i];
    }
    for (int i = tid; i < 256; i += 64) sVp[i] = Vp[(size_t)b*256 + i];
    __syncthreads();
    for (int pair = 0; pair < 9; ++pair) {
        int i = pair / 3, j = pair % 3;
        const float* Qj = sQ[j];
        const float* Ki = sK[i];
        float accp = 0.f;
        #pragma unroll
        for (int it = 0; it < 4; ++it) {
            int e = tid + 64*it;
            int d = e >> 4, ee = e & 15;
            float y = 0.f;
            #pragma unroll
            for (int f = 0; f < 16; ++f) {
                float dv = Qj[d*16 + f] - Ki[d*16 + f];
                float ev = Qj[ee*16 + f] - Ki[ee*16 + f];
                y = fmaf(dv, ev, y);
            }
            accp += y*y;
        }
        for (int off = 32; off > 0; off >>= 1) accp += __shfl_down(accp, off, 64);
        if (tid == 0) {
            float E = sqrtf(accp);
            ssc[pair] = 1.f / (1.f + log1pf(E));
        }
        __syncthreads();
    }
    if (tid < 3) {
        int j = tid;
        float e0 = expf(ssc[0*3 + j]), e1 = expf(ssc[1*3 + j]), e2 = expf(ssc[2*3 + j]);
        wj[j] = e2 / (e0 + e1 + e2);
    }
    __syncthreads();
    int o = tid >> 4, g = tid & 15;
    float part = 0.f;
    #pragma unroll
    for (int t = 0; t < 16; ++t) {
        int de = g*16 + t;
        float vv = sVp[de];
        float l0 = lw[o*768 + de];
        float l1 = lw[o*768 + 256 + de];
        float l2 = lw[o*768 + 512 + de];
        part = fmaf(vv, fmaf(wj[0], l0, fmaf(wj[1], l1, wj[2]*l2)), part);
    }
    for (int off = 8; off > 0; off >>= 1) part += __shfl_down(part, off, 16);
    if (g == 0) out[b*4 + o] = part + lb[o];
}

// ================= launch ==========
extern "C" void kernel_launch(void* const* d_in, const int* in_sizes, int n_in,
                              void* d_out, int out_size, void* d_ws, size_t ws_size,
                              hipStream_t stream) {
    const float* x  = (const float*)d_in[0];
    const float* w1 = (const float*)d_in[1];
    // d_in[2] conv1_b: cancels exactly in batch-norm (mean subtraction) -> unused
    const float* g1 = (const float*)d_in[3];
    const float* b1 = (const float*)d_in[4];
    const float* w2 = (const float*)d_in[5];
    // d_in[6] conv2_b: cancels exactly in batch-norm -> unused
    const float* g2 = (const float*)d_in[7];
    const float* b2 = (const float*)d_in[8];
    const float* wq = (const float*)d_in[9];
    const float* wk = (const float*)d_in[10];
    const float* wv = (const float*)d_in[11];
    const float* lw = (const float*)d_in[12];
    const float* lb = (const float*)d_in[13];

    float* ws   = (float*)d_ws;
    float* h1   = ws + OFF_H1;
    float* h2   = ws + OFF_H2;
    float* Sm   = ws + OFF_S;
    float* qqt  = ws + OFF_QQT;
    float* kkt  = ws + OFF_KKT;
    float* vpm  = ws + OFF_VP;
    float* p1a  = ws + OFF_P1;
    float* p2a  = ws + OFF_P2;
    float* bn1p = ws + OFF_BN1;
    float* bn2p = ws + OFF_BN2;

    k1_conv1<<<BSZ, 256, 0, stream>>>(x, w1, h1, p1a);
    k2_bn1<<<CEEG, 64, 0, stream>>>(p1a, g1, b1, bn1p);
    dim3 g3(BSZ, 8);
    k3_conv2<<<g3, 256, 0, stream>>>(h1, w2, bn1p, h2, p2a);
    k4_bn2<<<C2, 256, 0, stream>>>(p2a, g2, b2, bn2p);
    k5_gram<<<BSZ*3, 256, 0, stream>>>(h2, bn2p, Sm);
    k6_eig<<<BSZ*3, 64, 0, stream>>>(Sm, wq, wk, wv, qqt, kkt, vpm);
    k7_out<<<BSZ, 64, 0, stream>>>(qqt, kkt, vpm, lw, lb, (float*)d_out);
}

// Round 4
// 563.615 us; speedup vs baseline: 1.1720x; 1.1720x over previous
//
#include <hip/hip_runtime.h>
#include <math.h>

#define PDIM 8
#define BSZ 256
#define CEEG 22
#define TLEN 1000
#define KW 12
#define C2 96
#define TOUT 989
#define TSTR 992          // padded h2 row stride (16B-aligned float4 stores)
#define NSWEEP 8

// ---- workspace layout (in floats) ----
#define OFF_H1   ((size_t)0)
#define SZ_H1    ((size_t)BSZ*CEEG*TLEN)
#define OFF_H2   (OFF_H1 + SZ_H1)
#define SZ_H2    ((size_t)BSZ*C2*TSTR)
#define OFF_S    (OFF_H2 + SZ_H2)
#define SZ_S     ((size_t)BSZ*3*1024)
#define OFF_QQT  (OFF_S + SZ_S)
#define SZ_QQT   ((size_t)BSZ*3*256)
#define OFF_KKT  (OFF_QQT + SZ_QQT)
#define OFF_VP   (OFF_KKT + SZ_QQT)
#define SZ_VP    ((size_t)BSZ*256)
#define OFF_P1   (OFF_VP + SZ_VP)
#define SZ_P1    ((size_t)BSZ*44)
#define OFF_P2   (OFF_P1 + SZ_P1)
#define SZ_P2    ((size_t)BSZ*8*192)
#define OFF_BN1  (OFF_P2 + SZ_P2)
#define OFF_BN2  (OFF_BN1 + (size_t)64)

// ================= K1: conv1 (22ch spatial filter) + BN1 partial stats ==========
__global__ __launch_bounds__(256) void k1_conv1(const float* __restrict__ x,
        const float* __restrict__ w1, float* __restrict__ h1,
        float* __restrict__ part1) {
    __shared__ float sw[CEEG*CEEG];       // [o][c]
    __shared__ float red[4][44];
    int b = blockIdx.x;
    int tid = threadIdx.x;
    for (int i = tid; i < CEEG*CEEG; i += 256) sw[i] = w1[i];
    __syncthreads();
    float sum[CEEG], sumsq[CEEG];
    #pragma unroll
    for (int o = 0; o < CEEG; ++o) { sum[o] = 0.f; sumsq[o] = 0.f; }
    const float* xb = x + (size_t)b*CEEG*TLEN;
    float* hb = h1 + (size_t)b*CEEG*TLEN;
    for (int it = 0; it < 4; ++it) {
        int t = it*256 + tid;
        if (t < TLEN) {
            float acc[CEEG];
            #pragma unroll
            for (int o = 0; o < CEEG; ++o) acc[o] = 0.f;
            #pragma unroll 2
            for (int c = 0; c < CEEG; ++c) {
                float xv = xb[c*TLEN + t];
                #pragma unroll
                for (int o = 0; o < CEEG; ++o) acc[o] = fmaf(xv, sw[o*CEEG + c], acc[o]);
            }
            #pragma unroll
            for (int o = 0; o < CEEG; ++o) {
                hb[o*TLEN + t] = acc[o];
                sum[o]  += acc[o];
                sumsq[o] += acc[o]*acc[o];
            }
        }
    }
    int lane = tid & 63, wv = tid >> 6;
    #pragma unroll
    for (int o = 0; o < CEEG; ++o) {
        float s = sum[o], s2 = sumsq[o];
        for (int off = 32; off > 0; off >>= 1) {
            s  += __shfl_down(s,  off, 64);
            s2 += __shfl_down(s2, off, 64);
        }
        if (lane == 0) { red[wv][o] = s; red[wv][CEEG + o] = s2; }
    }
    __syncthreads();
    if (tid < 44) {
        part1[(size_t)b*44 + tid] = red[0][tid] + red[1][tid] + red[2][tid] + red[3][tid];
    }
}

// ================= K2: finalize BN1 params (1 block / channel) ==========
__global__ __launch_bounds__(64) void k2_bn1(const float* __restrict__ part1,
        const float* __restrict__ g, const float* __restrict__ bta, float* __restrict__ p1) {
    int c = blockIdx.x, t = threadIdx.x;
    float s = 0.f, s2 = 0.f;
    for (int blk = t; blk < BSZ; blk += 64) {
        s  += part1[(size_t)blk*44 + c];
        s2 += part1[(size_t)blk*44 + CEEG + c];
    }
    for (int off = 32; off > 0; off >>= 1) {
        s  += __shfl_down(s,  off, 64);
        s2 += __shfl_down(s2, off, 64);
    }
    if (t == 0) {
        double N = (double)BSZ * (double)TLEN;
        double mu = (double)s / N, var = (double)s2 / N - mu*mu;
        double scale = (double)g[c] / sqrt(var + 1e-5);
        p1[c] = (float)scale;
        p1[CEEG + c] = (float)((double)bta[c] - mu*scale);
    }
}

// ================= K3: conv2 (96x22x12) v2: 3o x 16t / thread, dbuf weights ====
__global__ __launch_bounds__(256) void k3_conv2(const float* __restrict__ h1,
        const float* __restrict__ w2, const float* __restrict__ p1,
        float* __restrict__ h2, float* __restrict__ part2) {
    __shared__ float sin_[CEEG][160];       // staged input (BN1+ELU), 16B-aligned rows
    __shared__ float swt[2][C2*14];         // double-buffered weights [o][14]
    __shared__ float rStat[C2][20];         // per-(o, tgroup) partial sums
    int b = blockIdx.x;
    int tile = blockIdx.y;                  // 0..7
    int t0 = tile * 128;
    int tid = threadIdx.x;
    int og = tid & 31;                      // o base = 3*og
    int tg = tid >> 5;                      // t base = 16*tg
    int ob = 3*og;
    const float* hb = h1 + (size_t)b*CEEG*TLEN;

    // stage input window [t0, t0+139] with BN1+ELU; zero beyond TLEN
    for (int i = tid; i < CEEG*140; i += 256) {
        int c = i / 140, tt = i - c*140;
        float v = 0.f;
        int t = t0 + tt;
        if (t < TLEN) {
            float z = fmaf(hb[c*TLEN + t], p1[c], p1[CEEG + c]);
            v = z > 0.f ? z : expm1f(z);
        }
        sin_[c][tt] = v;
    }
    // stage weights for c=0 into buf 0
    for (int i = tid; i < C2*KW; i += 256) {
        int o = i / KW, k = i - o*KW;
        swt[0][o*14 + k] = w2[o*264 + k];   // c=0
    }
    __syncthreads();

    float acc[3][16];
    #pragma unroll
    for (int j = 0; j < 3; ++j)
        #pragma unroll
        for (int i = 0; i < 16; ++i) acc[j][i] = 0.f;

    for (int c = 0; c < CEEG; ++c) {
        int buf = c & 1;
        // prefetch weights for c+1 into other buffer
        if (c + 1 < CEEG) {
            int cn = c + 1;
            for (int i = tid; i < C2*KW; i += 256) {
                int o = i / KW, k = i - o*KW;
                swt[buf ^ 1][o*14 + k] = w2[o*264 + cn*12 + k];
            }
        }
        // load this thread's weights (float2, 2-way bank alias = free)
        float aw[3][12];
        #pragma unroll
        for (int j = 0; j < 3; ++j) {
            const float2* wr = (const float2*)&swt[buf][(ob + j)*14];
            #pragma unroll
            for (int h = 0; h < 6; ++h) {
                float2 wv2 = wr[h];
                aw[j][2*h] = wv2.x; aw[j][2*h + 1] = wv2.y;
            }
        }
        // load input window (float4 broadcast: 2 distinct addrs per wave)
        float bw[28];
        const float4* br = (const float4*)&sin_[c][tg*16];
        #pragma unroll
        for (int h = 0; h < 7; ++h) {
            float4 bv = br[h];
            bw[4*h] = bv.x; bw[4*h+1] = bv.y; bw[4*h+2] = bv.z; bw[4*h+3] = bv.w;
        }
        #pragma unroll
        for (int k = 0; k < KW; ++k) {
            #pragma unroll
            for (int j = 0; j < 3; ++j) {
                float a = aw[j][k];
                #pragma unroll
                for (int i = 0; i < 16; ++i)
                    acc[j][i] = fmaf(a, bw[i + k], acc[j][i]);
            }
        }
        __syncthreads();
    }

    // stores + BN2 partial stats
    float* h2b = h2 + (size_t)b*C2*TSTR;
    int tbase = t0 + tg*16;
    #pragma unroll
    for (int j = 0; j < 3; ++j) {
        int o = ob + j;
        float s = 0.f, s2 = 0.f;
        if (tbase + 15 < TOUT) {
            float* dst = &h2b[(size_t)o*TSTR + tbase];
            #pragma unroll
            for (int h = 0; h < 4; ++h) {
                *(float4*)&dst[4*h] = make_float4(acc[j][4*h], acc[j][4*h+1], acc[j][4*h+2], acc[j][4*h+3]);
                #pragma unroll
                for (int u = 0; u < 4; ++u) {
                    float v = acc[j][4*h + u];
                    s += v; s2 += v*v;
                }
            }
        } else {
            #pragma unroll
            for (int i = 0; i < 16; ++i) {
                int t = tbase + i;
                if (t < TOUT) {
                    float v = acc[j][i];
                    h2b[(size_t)o*TSTR + t] = v;
                    s += v; s2 += v*v;
                }
            }
        }
        rStat[o][2*tg]     = s;
        rStat[o][2*tg + 1] = s2;
    }
    __syncthreads();
    if (tid < C2) {
        float s = 0.f, s2 = 0.f;
        #pragma unroll
        for (int g2 = 0; g2 < 8; ++g2) { s += rStat[tid][2*g2]; s2 += rStat[tid][2*g2+1]; }
        float* pb = part2 + ((size_t)b*8 + tile)*192;
        pb[tid] = s; pb[96 + tid] = s2;
    }
}

// ================= K4: finalize BN2 params (1 block / channel) ==========
__global__ __launch_bounds__(256) void k4_bn2(const float* __restrict__ part2,
        const float* __restrict__ g, const float* __restrict__ bta, float* __restrict__ p2) {
    __shared__ float rs[4], rs2[4];
    int q = blockIdx.x, t = threadIdx.x;
    float s = 0.f, s2 = 0.f;
    for (int blk = t; blk < BSZ*8; blk += 256) {
        s  += part2[(size_t)blk*192 + q];
        s2 += part2[(size_t)blk*192 + 96 + q];
    }
    for (int off = 32; off > 0; off >>= 1) {
        s  += __shfl_down(s,  off, 64);
        s2 += __shfl_down(s2, off, 64);
    }
    int lane = t & 63, wv = t >> 6;
    if (lane == 0) { rs[wv] = s; rs2[wv] = s2; }
    __syncthreads();
    if (t == 0) {
        double S  = (double)rs[0]  + rs[1]  + rs[2]  + rs[3];
        double S2 = (double)rs2[0] + rs2[1] + rs2[2] + rs2[3];
        double N = (double)BSZ * (double)TOUT;
        double mu = S / N, var = S2 / N - mu*mu;
        double scale = (double)g[q] / sqrt(var + 1e-5);
        p2[q] = (float)scale;
        p2[C2 + q] = (float)((double)bta[q] - mu*scale);
    }
}

// ================= K5: BN2+ELU fused Gram matrices S[b][m] = X X^T ==========
__global__ __launch_bounds__(256) void k5_gram(const float* __restrict__ h2,
        const float* __restrict__ p2, float* __restrict__ S) {
    __shared__ float sx[32][68];
    int bm = blockIdx.x;
    int b = bm / 3, m = bm % 3;
    int tid = threadIdx.x;
    int r0 = (tid >> 4) * 2;
    int c0 = (tid & 15) * 2;
    float a00 = 0.f, a01 = 0.f, a10 = 0.f, a11 = 0.f;
    const float* hb = h2 + ((size_t)b*C2 + m*32)*TSTR;
    int row = tid >> 3;
    int ts  = (tid & 7) * 8;
    float sc = p2[m*32 + row], sh = p2[C2 + m*32 + row];
    for (int t0 = 0; t0 < TOUT; t0 += 64) {
        __syncthreads();
        #pragma unroll
        for (int j = 0; j < 8; ++j) {
            int t = t0 + ts + j;
            float v = 0.f;
            if (t < TOUT) {
                float z = fmaf(hb[(size_t)row*TSTR + t], sc, sh);
                v = z > 0.f ? z : expm1f(z);
            }
            sx[row][ts + j] = v;
        }
        __syncthreads();
        #pragma unroll
        for (int tt = 0; tt < 64; tt += 4) {
            float4 va0 = *(const float4*)&sx[r0][tt];
            float4 va1 = *(const float4*)&sx[r0+1][tt];
            float4 vb0 = *(const float4*)&sx[c0][tt];
            float4 vb1 = *(const float4*)&sx[c0+1][tt];
            a00 = fmaf(va0.x, vb0.x, fmaf(va0.y, vb0.y, fmaf(va0.z, vb0.z, fmaf(va0.w, vb0.w, a00))));
            a01 = fmaf(va0.x, vb1.x, fmaf(va0.y, vb1.y, fmaf(va0.z, vb1.z, fmaf(va0.w, vb1.w, a01))));
            a10 = fmaf(va1.x, vb0.x, fmaf(va1.y, vb0.y, fmaf(va1.z, vb0.z, fmaf(va1.w, vb0.w, a10))));
            a11 = fmaf(va1.x, vb1.x, fmaf(va1.y, vb1.y, fmaf(va1.z, vb1.z, fmaf(va1.w, vb1.w, a11))));
        }
    }
    float* Sb = S + (size_t)bm*1024;
    Sb[r0*32 + c0]       = a00;
    Sb[r0*32 + c0 + 1]   = a01;
    Sb[(r0+1)*32 + c0]   = a10;
    Sb[(r0+1)*32 + c0+1] = a11;
}

// ================= K6: parallel Jacobi eigh v3: 256 thr/matrix, b64 V, f2 cs ======
__device__ __forceinline__ void pair_of(int r, int k, int& p, int& q) {
    if (k == 0) { p = r; q = 31; }
    else {
        int a = (r + k) % 31;
        int b2 = (r - k + 31) % 31;
        p = min(a, b2); q = max(a, b2);
    }
}

__global__ __launch_bounds__(256) void k6_eig(const float* __restrict__ S,
        const float* __restrict__ wq, const float* __restrict__ wk, const float* __restrict__ wv,
        float* __restrict__ QQt, float* __restrict__ KKt, float* __restrict__ Vp) {
    __shared__ float A[32][33];
    __shared__ float Vt[32][34];            // V transposed: Vt[col][row], even stride
    __shared__ float2 cs2[16];
    __shared__ float sW[3][512];
    __shared__ unsigned int ptab[31*16];
    __shared__ float Up[32][9];
    __shared__ float Aw[16][9];
    __shared__ float G[8][9];
    __shared__ float Lm[8][9];
    __shared__ float Mm[16][9];
    __shared__ float lam[32];
    int bm = blockIdx.x, b = bm / 3, m = bm % 3;
    int tid = threadIdx.x;
    const float* Sb = S + (size_t)bm*1024;
    for (int i = tid; i < 1024; i += 256) {
        int r_ = i >> 5, c_ = i & 31;
        A[r_][c_] = Sb[i];
        Vt[r_][c_] = (r_ == c_) ? 1.f : 0.f;
    }
    for (int i = tid; i < 512; i += 256) {
        sW[0][i] = wq[i]; sW[1][i] = wk[i]; sW[2][i] = wv[i];
    }
    for (int i = tid; i < 31*16; i += 256) {
        int r_ = i >> 4, k_ = i & 15;
        int p, q; pair_of(r_, k_, p, q);
        ptab[i] = (unsigned)p | ((unsigned)q << 16);
    }
    __syncthreads();

    int kk_ = tid >> 4, ll_ = tid & 15;
    int i0 = kk_ * 2;
    for (int sweep = 0; sweep < NSWEEP; ++sweep) {
        for (int r = 0; r < 31; ++r) {
            if (tid < 16) {
                unsigned pq = ptab[(r << 4) + tid];
                int p = pq & 0xffff, q = pq >> 16;
                float app = A[p][p], aqq = A[q][q], apq = A[p][q];
                float c = 1.f, s = 0.f;
                if (apq != 0.f) {
                    float tau = (aqq - app) / (2.f * apq);
                    float tt = (tau >= 0.f ? 1.f : -1.f) / (fabsf(tau) + sqrtf(1.f + tau*tau));
                    c = 1.f / sqrtf(1.f + tt*tt);
                    s = tt * c;
                    if (!(c == c) || !(s == s)) { c = 1.f; s = 0.f; }
                }
                cs2[tid] = make_float2(c, s);
            }
            __syncthreads();
            {
                unsigned pqk = ptab[(r << 4) + kk_];
                unsigned pql = ptab[(r << 4) + ll_];
                int p = pqk & 0xffff, q = pqk >> 16;
                int rr = pql & 0xffff, ss = pql >> 16;
                float2 ck2 = cs2[kk_], cl2 = cs2[ll_];
                float ck = ck2.x, sk = ck2.y, cl = cl2.x, sl = cl2.y;
                float apr = A[p][rr], aps = A[p][ss], aqr = A[q][rr], aqs = A[q][ss];
                float tpr = ck*apr - sk*aqr;
                float tqr = sk*apr + ck*aqr;
                float tps = ck*aps - sk*aqs;
                float tqs = sk*aps + ck*aqs;
                A[p][rr] = cl*tpr - sl*tps;
                A[p][ss] = sl*tpr + cl*tps;
                A[q][rr] = cl*tqr - sl*tqs;
                A[q][ss] = sl*tqr + cl*tqs;
                // V update (transposed layout): cols rr,ss of V = rows of Vt; 2 rows i0,i0+1
                float2 vr = *(const float2*)&Vt[rr][i0];
                float2 vs = *(const float2*)&Vt[ss][i0];
                float2 nvr, nvs;
                nvr.x = cl*vr.x - sl*vs.x;
                nvr.y = cl*vr.y - sl*vs.y;
                nvs.x = sl*vr.x + cl*vs.x;
                nvs.y = sl*vr.y + cl*vs.y;
                *(float2*)&Vt[rr][i0] = nvr;
                *(float2*)&Vt[ss][i0] = nvs;
            }
            __syncthreads();
        }
    }

    // top-8 eigenvalue selection (descending) -> Up (Up[row][rank] = Vt[col][row])
    if (tid < 32) lam[tid] = A[tid][tid];
    __syncthreads();
    if (tid < 32) {
        float lj = lam[tid];
        int rank = 0;
        #pragma unroll
        for (int i = 0; i < 32; ++i) {
            float li = lam[i];
            rank += (li > lj) || (li == lj && i < tid);
        }
        if (rank < PDIM) {
            #pragma unroll
            for (int i = 0; i < 32; ++i) Up[i][rank] = Vt[tid][i];
        }
    }
    __syncthreads();

    // projections: P = A (A^T A)^{-1} A^T for A = W * Up  (== qr(A).Q @ Q^T)
    for (int widx = 0; widx < 3; ++widx) {
        if (widx == 2 && m != 2) break;   // V-projection only needed for m==2
        const float* W = sW[widx];
        if (tid < 128) {
            int o = tid >> 3, pp = tid & 7;
            float s = 0.f;
            #pragma unroll
            for (int i = 0; i < 32; ++i) s = fmaf(W[o*32 + i], Up[i][pp], s);
            Aw[o][pp] = s;
        }
        __syncthreads();
        if (tid < 64) {
            int xx = tid >> 3, yy = tid & 7;
            float s = 0.f;
            #pragma unroll
            for (int o = 0; o < 16; ++o) s = fmaf(Aw[o][xx], Aw[o][yy], s);
            G[xx][yy] = s;
        }
        __syncthreads();
        if (tid == 0) {
            float Lr[8][8];
            #pragma unroll
            for (int jj = 0; jj < 8; ++jj) {
                float d = G[jj][jj];
                #pragma unroll
                for (int kk = 0; kk < 8; ++kk) if (kk < jj) d -= Lr[jj][kk]*Lr[jj][kk];
                d = sqrtf(fmaxf(d, 1e-30f));
                float inv = 1.f / d;
                Lr[jj][jj] = d;
                Lm[jj][jj] = inv;     // store INVERSE of diagonal
                #pragma unroll
                for (int ii = 0; ii < 8; ++ii) if (ii > jj) {
                    float v = G[ii][jj];
                    #pragma unroll
                    for (int kk = 0; kk < 8; ++kk) if (kk < jj) v -= Lr[ii][kk]*Lr[jj][kk];
                    v *= inv;
                    Lr[ii][jj] = v;
                    Lm[ii][jj] = v;
                }
            }
        }
        __syncthreads();
        if (tid < 16) {
            int o = tid;
            float a[8], mv[8];
            #pragma unroll
            for (int pp = 0; pp < 8; ++pp) a[pp] = Aw[o][pp];
            #pragma unroll
            for (int jj = 0; jj < 8; ++jj) {
                float v = a[jj];
                #pragma unroll
                for (int kk = 0; kk < 8; ++kk) if (kk < jj) v -= Lm[jj][kk]*mv[kk];
                mv[jj] = v * Lm[jj][jj];
            }
            #pragma unroll
            for (int pp = 0; pp < 8; ++pp) Mm[o][pp] = mv[pp];
        }
        __syncthreads();
        {
            int d = tid >> 4, e = tid & 15;
            float s = 0.f;
            #pragma unroll
            for (int pp = 0; pp < 8; ++pp) s = fmaf(Mm[d][pp], Mm[e][pp], s);
            float* dst = (widx == 0) ? (QQt + (size_t)bm*256)
                       : (widx == 1) ? (KKt + (size_t)bm*256)
                       : (Vp + (size_t)b*256);
            dst[d*16 + e] = s;
        }
        __syncthreads();
    }
}

// ================= K7: attention scores + softmax(i=2) + output linear ==========
__global__ __launch_bounds__(64) void k7_out(const float* __restrict__ QQt,
        const float* __restrict__ KKt, const float* __restrict__ Vp,
        const float* __restrict__ lw, const float* __restrict__ lb,
        float* __restrict__ out) {
    __shared__ float sQ[3][256], sK[3][256], sVp[256], ssc[9], wj[3];
    int b = blockIdx.x, tid = threadIdx.x;
    for (int i = tid; i < 768; i += 64) {
        sQ[i >> 8][i & 255] = QQt[(size_t)b*768 + i];
        sK[i >> 8][i & 255] = KKt[(size_t)b*768 + i];
    }
    for (int i = tid; i < 256; i += 64) sVp[i] = Vp[(size_t)b*256 + i];
    __syncthreads();
    for (int pair = 0; pair < 9; ++pair) {
        int i = pair / 3, j = pair % 3;
        const float* Qj = sQ[j];
        const float* Ki = sK[i];
        float accp = 0.f;
        #pragma unroll
        for (int it = 0; it < 4; ++it) {
            int e = tid + 64*it;
            int d = e >> 4, ee = e & 15;
            float y = 0.f;
            #pragma unroll
            for (int f = 0; f < 16; ++f) {
                float dv = Qj[d*16 + f] - Ki[d*16 + f];
                float ev = Qj[ee*16 + f] - Ki[ee*16 + f];
                y = fmaf(dv, ev, y);
            }
            accp += y*y;
        }
        for (int off = 32; off > 0; off >>= 1) accp += __shfl_down(accp, off, 64);
        if (tid == 0) {
            float E = sqrtf(accp);
            ssc[pair] = 1.f / (1.f + log1pf(E));
        }
        __syncthreads();
    }
    if (tid < 3) {
        int j = tid;
        float e0 = expf(ssc[0*3 + j]), e1 = expf(ssc[1*3 + j]), e2 = expf(ssc[2*3 + j]);
        wj[j] = e2 / (e0 + e1 + e2);
    }
    __syncthreads();
    int o = tid >> 4, g = tid & 15;
    float part = 0.f;
    #pragma unroll
    for (int t = 0; t < 16; ++t) {
        int de = g*16 + t;
        float vv = sVp[de];
        float l0 = lw[o*768 + de];
        float l1 = lw[o*768 + 256 + de];
        float l2 = lw[o*768 + 512 + de];
        part = fmaf(vv, fmaf(wj[0], l0, fmaf(wj[1], l1, wj[2]*l2)), part);
    }
    for (int off = 8; off > 0; off >>= 1) part += __shfl_down(part, off, 16);
    if (g == 0) out[b*4 + o] = part + lb[o];
}

// ================= launch ==========
extern "C" void kernel_launch(void* const* d_in, const int* in_sizes, int n_in,
                              void* d_out, int out_size, void* d_ws, size_t ws_size,
                              hipStream_t stream) {
    const float* x  = (const float*)d_in[0];
    const float* w1 = (const float*)d_in[1];
    // d_in[2] conv1_b: cancels exactly in batch-norm (mean subtraction) -> unused
    const float* g1 = (const float*)d_in[3];
    const float* b1 = (const float*)d_in[4];
    const float* w2 = (const float*)d_in[5];
    // d_in[6] conv2_b: cancels exactly in batch-norm -> unused
    const float* g2 = (const float*)d_in[7];
    const float* b2 = (const float*)d_in[8];
    const float* wq = (const float*)d_in[9];
    const float* wk = (const float*)d_in[10];
    const float* wv = (const float*)d_in[11];
    const float* lw = (const float*)d_in[12];
    const float* lb = (const float*)d_in[13];

    float* ws   = (float*)d_ws;
    float* h1   = ws + OFF_H1;
    float* h2   = ws + OFF_H2;
    float* Sm   = ws + OFF_S;
    float* qqt  = ws + OFF_QQT;
    float* kkt  = ws + OFF_KKT;
    float* vpm  = ws + OFF_VP;
    float* p1a  = ws + OFF_P1;
    float* p2a  = ws + OFF_P2;
    float* bn1p = ws + OFF_BN1;
    float* bn2p = ws + OFF_BN2;

    k1_conv1<<<BSZ, 256, 0, stream>>>(x, w1, h1, p1a);
    k2_bn1<<<CEEG, 64, 0, stream>>>(p1a, g1, b1, bn1p);
    dim3 g3(BSZ, 8);
    k3_conv2<<<g3, 256, 0, stream>>>(h1, w2, bn1p, h2, p2a);
    k4_bn2<<<C2, 256, 0, stream>>>(p2a, g2, b2, bn2p);
    k5_gram<<<BSZ*3, 256, 0, stream>>>(h2, bn2p, Sm);
    k6_eig<<<BSZ*3, 256, 0, stream>>>(Sm, wq, wk, wv, qqt, kkt, vpm);
    k7_out<<<BSZ, 64, 0, stream>>>(qqt, kkt, vpm, lw, lb, (float*)d_out);
}